// Round 1
// baseline (169.811 us; speedup 1.0000x reference)
//
#include <hip/hip_runtime.h>
#include <stdint.h>

// ---- types ----
typedef __attribute__((ext_vector_type(4))) float   f4;
typedef __attribute__((ext_vector_type(8))) short   short8;   // 8 x bf16 (MFMA A/B frag)
typedef __attribute__((ext_vector_type(4))) float   floatx4;  // MFMA C/D frag
typedef __attribute__((ext_vector_type(4))) unsigned int u32x4;

#define LN2F 0.6931471805599453f

// Problem constants
#define BB 65536
#define SS 512
#define DD 100
// K padded to 128 (4 k-steps of 32 for mfma 16x16x32 bf16)

__device__ __forceinline__ unsigned short f2bf(float f) {
  union { float f; unsigned int u; } v; v.f = f;
  unsigned int u = v.u;
  u += 0x7fffu + ((u >> 16) & 1u);   // RNE
  return (unsigned short)(u >> 16);
}
__device__ __forceinline__ u32x4 pack8(f4 a, f4 b) {
  u32x4 r;
  r.x = (unsigned int)f2bf(a[0]) | ((unsigned int)f2bf(a[1]) << 16);
  r.y = (unsigned int)f2bf(a[2]) | ((unsigned int)f2bf(a[3]) << 16);
  r.z = (unsigned int)f2bf(b[0]) | ((unsigned int)f2bf(b[1]) << 16);
  r.w = (unsigned int)f2bf(b[2]) | ((unsigned int)f2bf(b[3]) << 16);
  return r;
}
// numerically stable softplus(x) = log(1+e^x)
__device__ __forceinline__ float softplus_full(float x) {
  return fmaxf(x, 0.f) + log1pf(expf(-fabsf(x)));
}

// ---------------------------------------------------------------------------
// Kernel 1: gather + convert neg rows into MFMA B-fragment tiled layout in ws.
// Layout: 16B unit index = (sgroup*4 + kstep)*64 + (s&15) + 16*kquad
// Also zero-inits out[0].
// Junk lanes (kg>=13 a, kg>=12 b) are redirected into the row interior so the
// per-row fetch span is exactly [base, base+400) = always 4 cachelines (400B
// rows start at offsets mod 128 <= 112), instead of 5 lines for 7/8 rows.
// ---------------------------------------------------------------------------
__global__ __launch_bounds__(256) void negprep_k(
    const float* __restrict__ tail_table, const int* __restrict__ neg_idx,
    u32x4* __restrict__ nws, float* __restrict__ out) {
  if (blockIdx.x == 0 && threadIdx.x == 0) out[0] = 0.f;
  int tid = blockIdx.x * 256 + threadIdx.x;          // 32 blocks -> 8192 threads
  int s = tid >> 4, kg = tid & 15, k0 = kg * 8;      // 16 threads per s-row
  int nrow = neg_idx[s];
  const float* np = tail_table + (size_t)nrow * DD;  // rows 400B, 16B aligned
  const int aoff = (kg <= 12) ? k0     : 0;          // junk -> row interior
  const int boff = (kg <  12) ? k0 + 4 : 4;          // (coalesces, no extra line)
  f4 a = *(const f4*)(np + aoff);
  f4 b = *(const f4*)(np + boff);
  if (kg > 12)  a = (f4){0.f,0.f,0.f,0.f};
  if (kg >= 12) b = (f4){0.f,0.f,0.f,0.f};
  nws[((s >> 4) * 4 + (kg >> 2)) * 64 + (s & 15) + 16 * (kg & 3)] = pack8(a, b);
}

// ---------------------------------------------------------------------------
// Kernel 2: fused main. 1024 blocks x 256 thr; block owns 64 b-rows x all 512 s.
// Stage 1 is a max-MLP batched gather: every thread issues 16 unconditional
// global_load_dwordx4 (4 rows x head+tail) before any consumption;
// __launch_bounds__(256,4) gives the allocator 128 VGPRs to keep them all in
// flight (R3's VGPR=64 software-MLP cap was the 45.7us wall). Junk-lane
// offsets are clamped into the row so each 400B row fetches exactly 4
// cachelines (512B) instead of avg 624B -> -18% gather HBM traffic.
// Neg matmul: g-outer loop with all 4 A-frag row-tiles register-resident
// (64 VGPR) so each neg B-group is read from L2 exactly once (halves the
// 268MB of stage-2 L2 traffic the old 2-half loop caused). Bias C-init via
// per-group ds_read_b128 broadcast. Per-group ballot-guarded Taylor epilogue
// (16 logits/lane) with inline unrolled exact fallback (no scratch anywhere).
// ---------------------------------------------------------------------------
__global__ __launch_bounds__(256, 4) void keg_main(
    const float* __restrict__ head_table, const float* __restrict__ tail_table,
    const float* __restrict__ rel_vec,   const float* __restrict__ rel_bias,
    const int* __restrict__ head_idx,    const int* __restrict__ tail_idx,
    const u32x4* __restrict__ nws,       float* __restrict__ out) {
  __shared__ u32x4 exA4[1024];   // 64 rows x 128 k, A-frag tiled: 16KB
  __shared__ __align__(16) float bias_s[64];
  __shared__ float red[4];

  const int t = threadIdx.x;
  const int kg = t & 15, rid = t >> 4, k0 = kg * 8;
  const int bbase = blockIdx.x * 64;

  // rel fragments (masked; rel_vec has exactly 100 floats -> conditional)
  f4 ra = {0,0,0,0}, rb = {0,0,0,0};
  if (kg <= 12) ra = *(const f4*)(rel_vec + k0);       // kg==12: rel[96..99]
  if (kg <  12) rb = *(const f4*)(rel_vec + k0 + 4);

  // junk-lane offsets redirected into the row: fetch span stays 4 lines/row
  const int aoff = (kg <= 12) ? k0     : 0;
  const int boff = (kg <  12) ? k0 + 4 : 4;

  // ---- batched gather: addresses first, then 16 dwordx4 back-to-back ----
  const float* hp[4]; const float* tp[4];
  float biasv[4];
  #pragma unroll
  for (int p = 0; p < 4; ++p) {
    int R = bbase + p * 16 + rid;
    hp[p] = head_table + (size_t)head_idx[R] * DD;
    int trow = tail_idx[R];
    tp[p] = tail_table + (size_t)trow * DD;
    biasv[p] = rel_bias[trow];     // 16 lanes same addr -> broadcast
  }
  f4 ha[4], hb[4], ta[4], tb[4];
  #pragma unroll
  for (int p = 0; p < 4; ++p) {
    ha[p] = *(const f4*)(hp[p] + aoff);
    hb[p] = *(const f4*)(hp[p] + boff);
    ta[p] = *(const f4*)(tp[p] + aoff);
    tb[p] = *(const f4*)(tp[p] + boff);
  }

  float pos_acc = 0.f;
  #pragma unroll
  for (int p = 0; p < 4; ++p) {
    f4 e0 = ha[p] + ra, e1 = hb[p] + rb;
    if (kg > 12)  e0 = (f4){0.f,0.f,0.f,0.f};   // mask junk lanes
    if (kg >= 12) e1 = (f4){0.f,0.f,0.f,0.f};
    exA4[(p * 4 + (kg >> 2)) * 64 + rid + 16 * (kg & 3)] = pack8(e0, e1);
    // fp32 pos dot; e masked zero kills junk t contributions
    float d = e0[0]*ta[p][0] + e0[1]*ta[p][1] + e0[2]*ta[p][2] + e0[3]*ta[p][3]
            + e1[0]*tb[p][0] + e1[1]*tb[p][1] + e1[2]*tb[p][2] + e1[3]*tb[p][3];
    d += __shfl_xor(d, 1); d += __shfl_xor(d, 2);
    d += __shfl_xor(d, 4); d += __shfl_xor(d, 8);
    if (kg == 0) {
      bias_s[p * 16 + rid] = biasv[p];
      pos_acc += softplus_full(-(d + biasv[p]));   // -log_sigmoid(pos_logit)
    }
  }
  __syncthreads();

  // ---- neg matmul: A-frags for all 4 row-tiles resident; B read once/group --
  const int w = t >> 6, lane = t & 63, quad = lane >> 4;
  const short8* exAs = (const short8*)exA4;
  const short8* nf   = (const short8*)nws;

  short8 afr[4][4];                                // 64 VGPR, lives all stage 2
  #pragma unroll
  for (int mf = 0; mf < 4; ++mf)
    #pragma unroll
    for (int ks = 0; ks < 4; ++ks)
      afr[mf][ks] = exAs[(mf * 4 + ks) * 64 + lane];

  float nacc = 0.f;
  #pragma unroll 2
  for (int g = 0; g < 8; ++g) {
    int ng = w * 8 + g;
    short8 bfr[4];
    #pragma unroll
    for (int ks = 0; ks < 4; ++ks)
      bfr[ks] = nf[(ng * 4 + ks) * 64 + lane];     // L2-hot, read ONCE
    floatx4 acc[4];
    #pragma unroll
    for (int mf = 0; mf < 4; ++mf)                 // bias folded into C-init
      acc[mf] = *(const floatx4*)&bias_s[mf * 16 + quad * 4];
    #pragma unroll
    for (int ks = 0; ks < 4; ++ks)
      #pragma unroll
      for (int mf = 0; mf < 4; ++mf)
        acc[mf] = __builtin_amdgcn_mfma_f32_16x16x32_bf16(afr[mf][ks], bfr[ks], acc[mf], 0, 0, 0);
    // per-group guarded epilogue (16 logits/lane)
    float s1 = 0.f, s2 = 0.f, gmax = 0.f;
    #pragma unroll
    for (int mf = 0; mf < 4; ++mf)
      #pragma unroll
      for (int r = 0; r < 4; ++r) {
        float x = acc[mf][r];
        s1 += x;
        s2 = fmaf(x, x, s2);
        gmax = fmaxf(gmax, fabsf(x));              // fabs = input modifier
      }
    if (__ballot(gmax < 0.03f) == ~0ULL) {
      // deg-2 Taylor softplus: ln2 + x/2 + x^2/8, |err|<5e-9 for |x|<0.03
      nacc += fmaf(s1, 0.5f, fmaf(s2, 0.125f, 16.f * LN2F));
    } else {                                       // inline exact path, no scratch
      #pragma unroll
      for (int mf = 0; mf < 4; ++mf)
        #pragma unroll
        for (int r = 0; r < 4; ++r)
          nacc += softplus_full(acc[mf][r]);
    }
  }

  // ---- block reduce -> atomic accumulate (exact pow2 1/BB scale) ----
  float tot = nacc + pos_acc;
  #pragma unroll
  for (int off = 32; off; off >>= 1) tot += __shfl_down(tot, off);
  if (lane == 0) red[w] = tot;
  __syncthreads();
  if (t == 0)
    atomicAdd(out, (red[0] + red[1] + red[2] + red[3]) * (1.0f / (float)BB));
}

extern "C" void kernel_launch(void* const* d_in, const int* in_sizes, int n_in,
                              void* d_out, int out_size, void* d_ws, size_t ws_size,
                              hipStream_t stream) {
  const float* head_table = (const float*)d_in[0];
  const float* tail_table = (const float*)d_in[1];
  const float* rel_vec    = (const float*)d_in[2];
  const float* rel_bias   = (const float*)d_in[3];
  const int*   head_idx   = (const int*)d_in[4];
  const int*   tail_idx   = (const int*)d_in[5];
  const int*   neg_idx    = (const int*)d_in[6];
  float* out = (float*)d_out;

  u32x4* nws = (u32x4*)d_ws;                 // 512 x 128 bf16 = 131072 B

  negprep_k<<<32, 256, 0, stream>>>(tail_table, neg_idx, nws, out);
  keg_main<<<1024, 256, 0, stream>>>(head_table, tail_table, rel_vec, rel_bias,
                                     head_idx, tail_idx, (const u32x4*)nws, out);
}

// Round 2
// 163.843 us; speedup vs baseline: 1.0364x; 1.0364x over previous
//
#include <hip/hip_runtime.h>
#include <stdint.h>

// ---- types ----
typedef __attribute__((ext_vector_type(4))) float   f4;
typedef __attribute__((ext_vector_type(8))) short   short8;   // 8 x bf16 (MFMA A/B frag)
typedef __attribute__((ext_vector_type(4))) float   floatx4;  // MFMA C/D frag
typedef __attribute__((ext_vector_type(4))) unsigned int u32x4;

#define LN2F 0.6931471805599453f

// Problem constants
#define BB 65536
#define SS 512
#define DD 100
// K padded to 128 (4 k-steps of 32 for mfma 16x16x32 bf16)

// ---- workspace layout ----
#define WS_NWS_BYTES   (512 * 128 * 2)                    // 131072: neg B-frags
#define WS_EX_OFF      WS_NWS_BYTES
#define WS_EX_BYTES    (65536 * 128 * 2)                  // 16 MiB: ex A-frag tiles
#define WS_BIAS_OFF    (WS_EX_OFF + WS_EX_BYTES)
#define WS_BIAS_BYTES  (65536 * 4)
#define WS_POS_OFF     (WS_BIAS_OFF + WS_BIAS_BYTES)
#define WS_POS_BYTES   (4096 * 4)
#define WS_NEEDED      ((size_t)(WS_POS_OFF + WS_POS_BYTES))

__device__ __forceinline__ unsigned short f2bf(float f) {
  union { float f; unsigned int u; } v; v.f = f;
  unsigned int u = v.u;
  u += 0x7fffu + ((u >> 16) & 1u);   // RNE
  return (unsigned short)(u >> 16);
}
__device__ __forceinline__ u32x4 pack8(f4 a, f4 b) {
  u32x4 r;
  r.x = (unsigned int)f2bf(a[0]) | ((unsigned int)f2bf(a[1]) << 16);
  r.y = (unsigned int)f2bf(a[2]) | ((unsigned int)f2bf(a[3]) << 16);
  r.z = (unsigned int)f2bf(b[0]) | ((unsigned int)f2bf(b[1]) << 16);
  r.w = (unsigned int)f2bf(b[2]) | ((unsigned int)f2bf(b[3]) << 16);
  return r;
}
// numerically stable softplus(x) = log(1+e^x)
__device__ __forceinline__ float softplus_full(float x) {
  return fmaxf(x, 0.f) + log1pf(expf(-fabsf(x)));
}

// ---------------------------------------------------------------------------
// gpack_k: max-TLP gather/pack kernel. 4096 blocks x 256 thr, ~50 VGPR, no
// meaningful LDS -> 8 waves/EU, whole grid resident: every random 512B row
// fetch in the problem is in flight essentially simultaneously (the fused
// kernel's 50%-occupancy 4-round-per-CU gather was 1.25 TB/s; this isolates
// whether that was a structural MLP limit or the memory system's random-
// access ceiling). Each 16-lane group owns one (head,tail) pair: gathers
// both rows (junk lanes redirected into the row so each 400B row fetches
// exactly its 4-cacheline span), computes ex=h+rel, packs bf16 A-frags into
// ws in keg stage-2 tiled layout, computes fp32 pos-loss, block-reduces to
// ws_pos. Blocks 0..31 also do negprep (folded: saves a dispatch) and block
// 0 zero-inits out.
// ---------------------------------------------------------------------------
__global__ __launch_bounds__(256, 8) void gpack_k(
    const float* __restrict__ head_table, const float* __restrict__ tail_table,
    const float* __restrict__ rel_vec,   const float* __restrict__ rel_bias,
    const int* __restrict__ head_idx,    const int* __restrict__ tail_idx,
    const int* __restrict__ neg_idx,
    u32x4* __restrict__ nws, u32x4* __restrict__ ws_ex,
    float* __restrict__ ws_bias, float* __restrict__ ws_pos,
    float* __restrict__ out) {
  __shared__ float pr_s[4];
  const int t = threadIdx.x;
  const int kg = t & 15, grp = t >> 4, k0 = kg * 8;
  const int pr = blockIdx.x * 16 + grp;          // pair id 0..65535

  // junk-lane offsets redirected into the row: fetch span stays 4 lines/row
  const int aoff = (kg <= 12) ? k0     : 0;
  const int boff = (kg <  12) ? k0 + 4 : 4;

  if (blockIdx.x == 0 && t == 0) out[0] = 0.f;
  // folded negprep (first, so na/nb liveness doesn't stack on main gather)
  if (blockIdx.x < 32) {
    int tid = blockIdx.x * 256 + t;
    int s = tid >> 4;
    int nrow = neg_idx[s];
    const float* np = tail_table + (size_t)nrow * DD;
    f4 na = *(const f4*)(np + aoff);
    f4 nb = *(const f4*)(np + boff);
    if (kg > 12)  na = (f4){0.f,0.f,0.f,0.f};
    if (kg >= 12) nb = (f4){0.f,0.f,0.f,0.f};
    nws[((s >> 4) * 4 + (kg >> 2)) * 64 + (s & 15) + 16 * (kg & 3)] = pack8(na, nb);
  }

  // rel fragments (rel_vec has exactly 100 floats -> conditional)
  f4 ra = {0,0,0,0}, rb = {0,0,0,0};
  if (kg <= 12) ra = *(const f4*)(rel_vec + k0);
  if (kg <  12) rb = *(const f4*)(rel_vec + k0 + 4);

  const float* hp = head_table + (size_t)head_idx[pr] * DD;
  int trow = tail_idx[pr];
  const float* tp = tail_table + (size_t)trow * DD;
  float bias = rel_bias[trow];                   // 16 lanes same addr
  f4 ha = *(const f4*)(hp + aoff);
  f4 hb = *(const f4*)(hp + boff);
  f4 ta = *(const f4*)(tp + aoff);
  f4 tb = *(const f4*)(tp + boff);

  f4 e0 = ha + ra, e1 = hb + rb;
  if (kg > 12)  e0 = (f4){0.f,0.f,0.f,0.f};      // mask junk lanes
  if (kg >= 12) e1 = (f4){0.f,0.f,0.f,0.f};
  // pack into keg stage-2 A-frag tiled layout (64-row tiles)
  int blk = pr >> 6, mf = (pr >> 4) & 3, rid = pr & 15;
  ws_ex[blk * 1024 + (mf * 4 + (kg >> 2)) * 64 + rid + 16 * (kg & 3)] = pack8(e0, e1);

  // fp32 pos dot; masked-zero e kills junk t contributions
  float d = e0[0]*ta[0] + e0[1]*ta[1] + e0[2]*ta[2] + e0[3]*ta[3]
          + e1[0]*tb[0] + e1[1]*tb[1] + e1[2]*tb[2] + e1[3]*tb[3];
  d += __shfl_xor(d, 1); d += __shfl_xor(d, 2);
  d += __shfl_xor(d, 4); d += __shfl_xor(d, 8);
  float pos = 0.f;
  if (kg == 0) {
    ws_bias[pr] = bias;
    pos = softplus_full(-(d + bias));            // -log_sigmoid(pos_logit)
  }
  #pragma unroll
  for (int off = 32; off; off >>= 1) pos += __shfl_down(pos, off);
  if ((t & 63) == 0) pr_s[t >> 6] = pos;
  __syncthreads();
  if (t == 0) ws_pos[blockIdx.x] = pr_s[0] + pr_s[1] + pr_s[2] + pr_s[3];
}

// ---------------------------------------------------------------------------
// mm_k: slim matmul kernel. 1024 blocks x 256 thr; block owns 64 b-rows x all
// 512 s. Copies its packed A-frag slab (16KB, coalesced) + bias to LDS, then
// runs the proven register-lean 2-half stage-2 (round-0 structure: afr[2][4]
// =32 VGPR, B-frags re-read per half from L2-hot nws, ballot-guarded Taylor
// epilogue). Adds gpack's 4 pos partials at the final atomic.
// ---------------------------------------------------------------------------
__global__ __launch_bounds__(256, 4) void mm_k(
    const u32x4* __restrict__ nws, const u32x4* __restrict__ ws_ex,
    const float* __restrict__ ws_bias, const float* __restrict__ ws_pos,
    float* __restrict__ out) {
  __shared__ u32x4 exA4[1024];   // 64 rows x 128 k, A-frag tiled: 16KB
  __shared__ __align__(16) float bias_s[64];
  __shared__ float red[4];
  const int t = threadIdx.x;

  #pragma unroll
  for (int i = 0; i < 4; ++i)
    exA4[i * 256 + t] = ws_ex[(size_t)blockIdx.x * 1024 + i * 256 + t];
  if (t < 64) bias_s[t] = ws_bias[blockIdx.x * 64 + t];
  __syncthreads();

  const int w = t >> 6, lane = t & 63, quad = lane >> 4;
  const short8* exAs = (const short8*)exA4;
  const short8* nf   = (const short8*)nws;
  float nacc = 0.f;
  #pragma unroll
  for (int h = 0; h < 2; ++h) {
    short8 afr[2][4];
    float  br[2][4];
    #pragma unroll
    for (int m = 0; m < 2; ++m) {
      int mf = h * 2 + m;
      #pragma unroll
      for (int ks = 0; ks < 4; ++ks) afr[m][ks] = exAs[(mf * 4 + ks) * 64 + lane];
      #pragma unroll
      for (int r = 0; r < 4; ++r)   br[m][r]  = bias_s[mf * 16 + quad * 4 + r];
    }
    #pragma unroll 2
    for (int g = 0; g < 8; ++g) {
      int ng = w * 8 + g;
      short8 bfr[4];
      #pragma unroll
      for (int ks = 0; ks < 4; ++ks)
        bfr[ks] = nf[(ng * 4 + ks) * 64 + lane];   // L2-hot
      floatx4 acc[2];
      #pragma unroll
      for (int m = 0; m < 2; ++m) {                // bias folded into C-init
        floatx4 c; c[0]=br[m][0]; c[1]=br[m][1]; c[2]=br[m][2]; c[3]=br[m][3];
        acc[m] = c;
      }
      #pragma unroll
      for (int ks = 0; ks < 4; ++ks)
        #pragma unroll
        for (int m = 0; m < 2; ++m)
          acc[m] = __builtin_amdgcn_mfma_f32_16x16x32_bf16(afr[m][ks], bfr[ks], acc[m], 0, 0, 0);
      // per-group guarded epilogue (8 logits/lane)
      float s1 = 0.f, s2 = 0.f, gmax = 0.f;
      #pragma unroll
      for (int m = 0; m < 2; ++m)
        #pragma unroll
        for (int r = 0; r < 4; ++r) {
          float x = acc[m][r];
          s1 += x;
          s2 = fmaf(x, x, s2);
          gmax = fmaxf(gmax, fabsf(x));            // fabs = input modifier
        }
      if (__ballot(gmax < 0.03f) == ~0ULL) {
        // deg-2 Taylor softplus: ln2 + x/2 + x^2/8, |err|<5e-9 for |x|<0.03
        nacc += fmaf(s1, 0.5f, fmaf(s2, 0.125f, 8.f * LN2F));
      } else {                                     // inline exact path, no scratch
        #pragma unroll
        for (int m = 0; m < 2; ++m)
          #pragma unroll
          for (int r = 0; r < 4; ++r)
            nacc += softplus_full(acc[m][r]);
      }
    }
  }

  // ---- block reduce -> atomic accumulate (exact pow2 1/BB scale) ----
  #pragma unroll
  for (int off = 32; off; off >>= 1) nacc += __shfl_down(nacc, off);
  if (lane == 0) red[w] = nacc;
  __syncthreads();
  if (t == 0) {
    const float* pp = ws_pos + blockIdx.x * 4;
    float tot = red[0] + red[1] + red[2] + red[3] + pp[0] + pp[1] + pp[2] + pp[3];
    atomicAdd(out, tot * (1.0f / (float)BB));
  }
}

// ---------------------------------------------------------------------------
// Fallback fused path (used only if ws_size < WS_NEEDED): round-0 proven
// kernels — negprep + fused gather/matmul with register-lean 2-half stage 2.
// ---------------------------------------------------------------------------
__global__ __launch_bounds__(256) void negprep_k(
    const float* __restrict__ tail_table, const int* __restrict__ neg_idx,
    u32x4* __restrict__ nws, float* __restrict__ out) {
  if (blockIdx.x == 0 && threadIdx.x == 0) out[0] = 0.f;
  int tid = blockIdx.x * 256 + threadIdx.x;
  int s = tid >> 4, kg = tid & 15, k0 = kg * 8;
  int nrow = neg_idx[s];
  const float* np = tail_table + (size_t)nrow * DD;
  const int aoff = (kg <= 12) ? k0     : 0;
  const int boff = (kg <  12) ? k0 + 4 : 4;
  f4 a = *(const f4*)(np + aoff);
  f4 b = *(const f4*)(np + boff);
  if (kg > 12)  a = (f4){0.f,0.f,0.f,0.f};
  if (kg >= 12) b = (f4){0.f,0.f,0.f,0.f};
  nws[((s >> 4) * 4 + (kg >> 2)) * 64 + (s & 15) + 16 * (kg & 3)] = pack8(a, b);
}

__global__ __launch_bounds__(256, 4) void keg_fused(
    const float* __restrict__ head_table, const float* __restrict__ tail_table,
    const float* __restrict__ rel_vec,   const float* __restrict__ rel_bias,
    const int* __restrict__ head_idx,    const int* __restrict__ tail_idx,
    const u32x4* __restrict__ nws,       float* __restrict__ out) {
  __shared__ u32x4 exA4[1024];
  __shared__ __align__(16) float bias_s[64];
  __shared__ float red[4];

  const int t = threadIdx.x;
  const int kg = t & 15, rid = t >> 4, k0 = kg * 8;
  const int bbase = blockIdx.x * 64;

  f4 ra = {0,0,0,0}, rb = {0,0,0,0};
  if (kg <= 12) ra = *(const f4*)(rel_vec + k0);
  if (kg <  12) rb = *(const f4*)(rel_vec + k0 + 4);
  const int aoff = (kg <= 12) ? k0     : 0;
  const int boff = (kg <  12) ? k0 + 4 : 4;

  const float* hp[4]; const float* tp[4];
  float biasv[4];
  #pragma unroll
  for (int p = 0; p < 4; ++p) {
    int R = bbase + p * 16 + rid;
    hp[p] = head_table + (size_t)head_idx[R] * DD;
    int trow = tail_idx[R];
    tp[p] = tail_table + (size_t)trow * DD;
    biasv[p] = rel_bias[trow];
  }
  f4 ha[4], hb[4], ta[4], tb[4];
  #pragma unroll
  for (int p = 0; p < 4; ++p) {
    ha[p] = *(const f4*)(hp[p] + aoff);
    hb[p] = *(const f4*)(hp[p] + boff);
    ta[p] = *(const f4*)(tp[p] + aoff);
    tb[p] = *(const f4*)(tp[p] + boff);
  }

  float pos_acc = 0.f;
  #pragma unroll
  for (int p = 0; p < 4; ++p) {
    f4 e0 = ha[p] + ra, e1 = hb[p] + rb;
    if (kg > 12)  e0 = (f4){0.f,0.f,0.f,0.f};
    if (kg >= 12) e1 = (f4){0.f,0.f,0.f,0.f};
    exA4[(p * 4 + (kg >> 2)) * 64 + rid + 16 * (kg & 3)] = pack8(e0, e1);
    float d = e0[0]*ta[p][0] + e0[1]*ta[p][1] + e0[2]*ta[p][2] + e0[3]*ta[p][3]
            + e1[0]*tb[p][0] + e1[1]*tb[p][1] + e1[2]*tb[p][2] + e1[3]*tb[p][3];
    d += __shfl_xor(d, 1); d += __shfl_xor(d, 2);
    d += __shfl_xor(d, 4); d += __shfl_xor(d, 8);
    if (kg == 0) {
      bias_s[p * 16 + rid] = biasv[p];
      pos_acc += softplus_full(-(d + biasv[p]));
    }
  }
  __syncthreads();

  const int w = t >> 6, lane = t & 63, quad = lane >> 4;
  const short8* exAs = (const short8*)exA4;
  const short8* nf   = (const short8*)nws;
  float nacc = 0.f;
  #pragma unroll
  for (int h = 0; h < 2; ++h) {
    short8 afr[2][4];
    float  br[2][4];
    #pragma unroll
    for (int m = 0; m < 2; ++m) {
      int mf = h * 2 + m;
      #pragma unroll
      for (int ks = 0; ks < 4; ++ks) afr[m][ks] = exAs[(mf * 4 + ks) * 64 + lane];
      #pragma unroll
      for (int r = 0; r < 4; ++r)   br[m][r]  = bias_s[mf * 16 + quad * 4 + r];
    }
    #pragma unroll 2
    for (int g = 0; g < 8; ++g) {
      int ng = w * 8 + g;
      short8 bfr[4];
      #pragma unroll
      for (int ks = 0; ks < 4; ++ks)
        bfr[ks] = nf[(ng * 4 + ks) * 64 + lane];
      floatx4 acc[2];
      #pragma unroll
      for (int m = 0; m < 2; ++m) {
        floatx4 c; c[0]=br[m][0]; c[1]=br[m][1]; c[2]=br[m][2]; c[3]=br[m][3];
        acc[m] = c;
      }
      #pragma unroll
      for (int ks = 0; ks < 4; ++ks)
        #pragma unroll
        for (int m = 0; m < 2; ++m)
          acc[m] = __builtin_amdgcn_mfma_f32_16x16x32_bf16(afr[m][ks], bfr[ks], acc[m], 0, 0, 0);
      float s1 = 0.f, s2 = 0.f, gmax = 0.f;
      #pragma unroll
      for (int m = 0; m < 2; ++m)
        #pragma unroll
        for (int r = 0; r < 4; ++r) {
          float x = acc[m][r];
          s1 += x;
          s2 = fmaf(x, x, s2);
          gmax = fmaxf(gmax, fabsf(x));
        }
      if (__ballot(gmax < 0.03f) == ~0ULL) {
        nacc += fmaf(s1, 0.5f, fmaf(s2, 0.125f, 8.f * LN2F));
      } else {
        #pragma unroll
        for (int m = 0; m < 2; ++m)
          #pragma unroll
          for (int r = 0; r < 4; ++r)
            nacc += softplus_full(acc[m][r]);
      }
    }
  }

  float tot = nacc + pos_acc;
  #pragma unroll
  for (int off = 32; off; off >>= 1) tot += __shfl_down(tot, off);
  if (lane == 0) red[w] = tot;
  __syncthreads();
  if (t == 0)
    atomicAdd(out, (red[0] + red[1] + red[2] + red[3]) * (1.0f / (float)BB));
}

extern "C" void kernel_launch(void* const* d_in, const int* in_sizes, int n_in,
                              void* d_out, int out_size, void* d_ws, size_t ws_size,
                              hipStream_t stream) {
  const float* head_table = (const float*)d_in[0];
  const float* tail_table = (const float*)d_in[1];
  const float* rel_vec    = (const float*)d_in[2];
  const float* rel_bias   = (const float*)d_in[3];
  const int*   head_idx   = (const int*)d_in[4];
  const int*   tail_idx   = (const int*)d_in[5];
  const int*   neg_idx    = (const int*)d_in[6];
  float* out = (float*)d_out;

  char* wsb = (char*)d_ws;
  u32x4* nws = (u32x4*)wsb;                        // 128 KiB neg B-frags

  if (ws_size >= WS_NEEDED) {
    u32x4* ws_ex   = (u32x4*)(wsb + WS_EX_OFF);
    float* ws_bias = (float*)(wsb + WS_BIAS_OFF);
    float* ws_pos  = (float*)(wsb + WS_POS_OFF);
    gpack_k<<<4096, 256, 0, stream>>>(head_table, tail_table, rel_vec, rel_bias,
                                      head_idx, tail_idx, neg_idx,
                                      nws, ws_ex, ws_bias, ws_pos, out);
    mm_k<<<1024, 256, 0, stream>>>((const u32x4*)nws, (const u32x4*)ws_ex,
                                   (const float*)ws_bias, (const float*)ws_pos, out);
  } else {
    negprep_k<<<32, 256, 0, stream>>>(tail_table, neg_idx, nws, out);
    keg_fused<<<1024, 256, 0, stream>>>(head_table, tail_table, rel_vec, rel_bias,
                                        head_idx, tail_idx, (const u32x4*)nws, out);
  }
}